// Round 1
// baseline (338.255 us; speedup 1.0000x reference)
//
#include <hip/hip_runtime.h>
#include <math.h>

// warpLayer: out[n,h,w,0:8] = bilinear(weight, angle-coords(image)) * 5e-4
//            out[n,h,w,8:12] = image[n,h,w,:]
// image: (16,512,512,4) fp32 ; weight: (256,256,8) fp32 ; out: (16,512,512,12) fp32

#define GH 256
#define GW 256
#define GC 8

__device__ __forceinline__ float4 f4_mad(float4 a, float s, float4 acc) {
    acc.x = fmaf(a.x, s, acc.x);
    acc.y = fmaf(a.y, s, acc.y);
    acc.z = fmaf(a.z, s, acc.z);
    acc.w = fmaf(a.w, s, acc.w);
    return acc;
}

__global__ __launch_bounds__(256) void warp_kernel(
    const float4* __restrict__ img,    // npix pixels, 4 channels each
    const float*  __restrict__ weight, // GH*GW*GC floats
    float4*       __restrict__ out,    // npix * 3 float4 (12 floats/pixel)
    int npix)
{
    int p = blockIdx.x * blockDim.x + threadIdx.x;
    if (p >= npix) return;

    float4 px = img[p];

    const float PI = 3.14159265358979323846f;
    const float SCALE = 255.0f / (2.0f * PI);  // (GH-1)/(2*pi), GH==GW

    // C0 from (ch0, ch1): pi - atan2(ch1, -ch0), scaled
    float c0 = (PI - atan2f(px.y, -px.x)) * SCALE;
    // C1 from (ch2, ch3)
    float c1 = (PI - atan2f(px.w, -px.z)) * SCALE;

    c0 = fminf(fmaxf(c0, 0.0f), 254.0f);
    c1 = fminf(fmaxf(c1, 0.0f), 254.0f);

    int i0 = (int)c0;           // c0 >= 0 so trunc == floor
    int j0 = (int)c1;
    float w0 = c0 - (float)i0;
    float w1 = c1 - (float)j0;

    float f00 = (1.0f - w0) * (1.0f - w1);
    float f10 = w0 * (1.0f - w1);
    float f01 = (1.0f - w0) * w1;
    float f11 = w0 * w1;

    // weight as float4: each (i,j) cell is 2 float4s; (i,j) and (i,j+1) contiguous.
    const float4* wq = (const float4*)weight;
    int b00 = (i0 * GW + j0) * 2;       // float4 index of corner (0,0)
    int b10 = b00 + GW * 2;             // row i0+1

    float4 q00a = wq[b00],     q00b = wq[b00 + 1];
    float4 q01a = wq[b00 + 2], q01b = wq[b00 + 3];
    float4 q10a = wq[b10],     q10b = wq[b10 + 1];
    float4 q11a = wq[b10 + 2], q11b = wq[b10 + 3];

    float4 ra = make_float4(0.f, 0.f, 0.f, 0.f);
    ra = f4_mad(q00a, f00, ra);
    ra = f4_mad(q10a, f10, ra);
    ra = f4_mad(q01a, f01, ra);
    ra = f4_mad(q11a, f11, ra);

    float4 rb = make_float4(0.f, 0.f, 0.f, 0.f);
    rb = f4_mad(q00b, f00, rb);
    rb = f4_mad(q10b, f10, rb);
    rb = f4_mad(q01b, f01, rb);
    rb = f4_mad(q11b, f11, rb);

    const float OUT_SCALE = 0.0005f;
    ra.x *= OUT_SCALE; ra.y *= OUT_SCALE; ra.z *= OUT_SCALE; ra.w *= OUT_SCALE;
    rb.x *= OUT_SCALE; rb.y *= OUT_SCALE; rb.z *= OUT_SCALE; rb.w *= OUT_SCALE;

    int ob = p * 3;
    out[ob]     = ra;
    out[ob + 1] = rb;
    out[ob + 2] = px;
}

extern "C" void kernel_launch(void* const* d_in, const int* in_sizes, int n_in,
                              void* d_out, int out_size, void* d_ws, size_t ws_size,
                              hipStream_t stream) {
    const float4* img    = (const float4*)d_in[0];
    const float*  weight = (const float*)d_in[1];
    float4*       out    = (float4*)d_out;

    int npix = in_sizes[0] / 4;           // 16*512*512 = 4,194,304
    int block = 256;
    int grid = (npix + block - 1) / block;

    warp_kernel<<<grid, block, 0, stream>>>(img, weight, out, npix);
}

// Round 2
// 282.351 us; speedup vs baseline: 1.1980x; 1.1980x over previous
//
#include <hip/hip_runtime.h>
#include <math.h>

// warpLayer: out[n,h,w,0:8] = bilinear(weight, angle-coords(image)) * 5e-4
//            out[n,h,w,8:12] = image[n,h,w,:]
// image: (16,512,512,4) fp32 ; weight: (256,256,8) fp32 ; out: (16,512,512,12) fp32
//
// R2 strategy: every global memory instruction 64B-coalesced.
//  - weight gather: 4 consecutive lanes load the 4 consecutive float4s of one
//    64B weight row -> single 64B L2 request (vs 64 divergent 16B requests).
//  - stores: stage 12 KB of results in LDS, write 3 contiguous float4 bursts.
//  - LDS gather buffer XOR-swizzled (chunk ^ (p&7)) -> conflict-free phases.

#define GH 256
#define GW 256

__device__ __forceinline__ float4 f4_mad(float4 a, float s, float4 acc) {
    acc.x = fmaf(a.x, s, acc.x);
    acc.y = fmaf(a.y, s, acc.y);
    acc.z = fmaf(a.z, s, acc.z);
    acc.w = fmaf(a.w, s, acc.w);
    return acc;
}

__global__ __launch_bounds__(256) void warp_kernel(
    const float4* __restrict__ img,    // npix pixels
    const float4* __restrict__ wq,     // weight as float4: GH*GW*2 entries
    float4*       __restrict__ out,    // npix*3 float4
    int npix)
{
    __shared__ float4 lds_g[2048];     // 32 KB gather buffer; reused as out-stage (768 used)
    __shared__ int    lds_a[256];      // per-pixel float4-index of weight row i0

    const int t    = threadIdx.x;
    const int base = blockIdx.x * 256;

    const float PI    = 3.14159265358979323846f;
    const float SCALE = 255.0f / (2.0f * PI);
    const float OUT_SCALE = 0.0005f;

    if (base + 256 > npix) {
        // tail fallback (not taken for the benchmark size; kept for safety)
        int p = base + t;
        if (p >= npix) return;
        float4 px = img[p];
        float c0 = (PI - atan2f(px.y, -px.x)) * SCALE;
        float c1 = (PI - atan2f(px.w, -px.z)) * SCALE;
        c0 = fminf(fmaxf(c0, 0.0f), 254.0f);
        c1 = fminf(fmaxf(c1, 0.0f), 254.0f);
        int i0 = (int)c0, j0 = (int)c1;
        float w0 = c0 - (float)i0, w1 = c1 - (float)j0;
        float f00 = (1.0f - w0) * (1.0f - w1), f10 = w0 * (1.0f - w1);
        float f01 = (1.0f - w0) * w1,          f11 = w0 * w1;
        int b00 = (i0 * GW + j0) * 2, b10 = b00 + GW * 2;
        float4 ra = make_float4(0,0,0,0), rb = make_float4(0,0,0,0);
        ra = f4_mad(wq[b00],   f00, ra); rb = f4_mad(wq[b00+1], f00, rb);
        ra = f4_mad(wq[b00+2], f01, ra); rb = f4_mad(wq[b00+3], f01, rb);
        ra = f4_mad(wq[b10],   f10, ra); rb = f4_mad(wq[b10+1], f10, rb);
        ra = f4_mad(wq[b10+2], f11, ra); rb = f4_mad(wq[b10+3], f11, rb);
        ra.x*=OUT_SCALE; ra.y*=OUT_SCALE; ra.z*=OUT_SCALE; ra.w*=OUT_SCALE;
        rb.x*=OUT_SCALE; rb.y*=OUT_SCALE; rb.z*=OUT_SCALE; rb.w*=OUT_SCALE;
        int ob = p * 3;
        out[ob] = ra; out[ob+1] = rb; out[ob+2] = px;
        return;
    }

    // ---- Phase 1: per-pixel coords ----
    int p = base + t;
    float4 px = img[p];
    float c0 = (PI - atan2f(px.y, -px.x)) * SCALE;
    float c1 = (PI - atan2f(px.w, -px.z)) * SCALE;
    c0 = fminf(fmaxf(c0, 0.0f), 254.0f);
    c1 = fminf(fmaxf(c1, 0.0f), 254.0f);
    int i0 = (int)c0, j0 = (int)c1;
    float w0 = c0 - (float)i0, w1 = c1 - (float)j0;
    lds_a[t] = (i0 * GW + j0) * 2;     // float4 index of 64B row (i0, j0..j0+1)
    __syncthreads();

    // ---- Phase 2: cooperative coalesced gather ----
    // 256 pixels x 8 chunks (16B) = 2048 chunks; chunk = h*4+c, h=row, c=float4-in-row.
    // 4 consecutive lanes -> 4 consecutive float4s of one row -> one 64B request.
    #pragma unroll
    for (int k = 0; k < 8; k++) {
        int g  = t + (k << 8);
        int pp = g >> 3;
        int hc = g & 7;
        int h  = hc >> 2;
        int c  = hc & 3;
        int addr = lds_a[pp] + h * (GW * 2) + c;
        float4 v = wq[addr];
        lds_g[pp * 8 + (hc ^ (pp & 7))] = v;   // XOR-swizzled store
    }
    __syncthreads();

    // ---- Phase 3: read own 8 chunks, blend ----
    float4 q[8];
    #pragma unroll
    for (int c2 = 0; c2 < 8; c2++)
        q[c2] = lds_g[t * 8 + (c2 ^ (t & 7))];

    float f00 = (1.0f - w0) * (1.0f - w1);
    float f10 = w0 * (1.0f - w1);
    float f01 = (1.0f - w0) * w1;
    float f11 = w0 * w1;

    // chunks: 0,1 = (i0,j0) ; 2,3 = (i0,j0+1) ; 4,5 = (i0+1,j0) ; 6,7 = (i0+1,j0+1)
    float4 ra = make_float4(0,0,0,0), rb = make_float4(0,0,0,0);
    ra = f4_mad(q[0], f00, ra); rb = f4_mad(q[1], f00, rb);
    ra = f4_mad(q[2], f01, ra); rb = f4_mad(q[3], f01, rb);
    ra = f4_mad(q[4], f10, ra); rb = f4_mad(q[5], f10, rb);
    ra = f4_mad(q[6], f11, ra); rb = f4_mad(q[7], f11, rb);
    ra.x*=OUT_SCALE; ra.y*=OUT_SCALE; ra.z*=OUT_SCALE; ra.w*=OUT_SCALE;
    rb.x*=OUT_SCALE; rb.y*=OUT_SCALE; rb.z*=OUT_SCALE; rb.w*=OUT_SCALE;

    // ---- Phase 4: stage results in LDS, coalesced store ----
    __syncthreads();
    lds_g[t * 3 + 0] = ra;
    lds_g[t * 3 + 1] = rb;
    lds_g[t * 3 + 2] = px;
    __syncthreads();

    int ob = base * 3;
    out[ob + t]       = lds_g[t];
    out[ob + 256 + t] = lds_g[256 + t];
    out[ob + 512 + t] = lds_g[512 + t];
}

extern "C" void kernel_launch(void* const* d_in, const int* in_sizes, int n_in,
                              void* d_out, int out_size, void* d_ws, size_t ws_size,
                              hipStream_t stream) {
    const float4* img = (const float4*)d_in[0];
    const float4* wq  = (const float4*)d_in[1];
    float4*       out = (float4*)d_out;

    int npix = in_sizes[0] / 4;           // 16*512*512 = 4,194,304
    int block = 256;
    int grid = (npix + block - 1) / block;

    warp_kernel<<<grid, block, 0, stream>>>(img, wq, out, npix);
}